// Round 1
// baseline (1184.392 us; speedup 1.0000x reference)
//
#include <hip/hip_runtime.h>
#include <cstdint>
#include <cstddef>

#define EPSC 1e-10f

// ---- workspace layout (float offsets) ----
// X transposed buffers (c,N) per (level,b): sizes 512000,1024000,2048000,4194304
#define RNX_OFF 15556608u
#define RNY_OFF 15588800u
#define RMIN_OFF 15620992u
#define CMIN_OFF 15653184u
#define MUX_OFF 15685376u
#define MUY_OFF 15693056u
#define COVS_OFF 15700736u
#define ACC_OFF 15700768u
// total ws use: 15700769 floats ~= 60 MB

struct Tabs {
  int c[4], N[4];
  unsigned xoff[4], yoff[4];
  int ro[4], mo[4];
};

// ---------------- K0: init mins/accumulators ----------------
__global__ void k_init(float* __restrict__ ws) {
  int i = blockIdx.x * blockDim.x + threadIdx.x;
  if (i < 64384) ((unsigned*)(ws + RMIN_OFF))[i] = 0x7f800000u; // RMIN+CMIN -> +inf
  if (i < 33) ws[COVS_OFF + i] = 0.f;                           // COVS[32] + ACC[1]
}

// ---------------- K1: gather -> transposed (c,N) ----------------
__global__ void k_gather(const float* __restrict__ tsrc, const float* __restrict__ gsrc,
                         const int* __restrict__ idx,
                         float* __restrict__ xt, float* __restrict__ yt,
                         int c, int hw, int N) {
  // grid (ceil(N/256), c, 16=which*8+b), block 256
  int z = blockIdx.z, which = z >> 3, b = z & 7;
  int ch = blockIdx.y;
  int n = blockIdx.x * 256 + threadIdx.x;
  if (n >= N) return;
  const float* src = which ? gsrc : tsrc;
  float* dst = which ? yt : xt;
  int sp = idx ? idx[b * N + n] : n;
  dst[((size_t)b * c + ch) * N + n] = src[((size_t)b * c + ch) * hw + sp];
}

// ---------------- K2: reciprocal norms 1/(||x||+eps) ----------------
__global__ void k_rnorm(float* __restrict__ ws, Tabs t) {
  // grid (4, 16, 4 levels), block 256; thread per n, loop over c (coalesced)
  int L = blockIdx.z;
  int c = t.c[L], N = t.N[L];
  int z = blockIdx.y, which = z >> 3, b = z & 7;
  int n = blockIdx.x * 256 + threadIdx.x;
  if (n >= N) return;
  const float* P = ws + (which ? t.yoff[L] : t.xoff[L]) + (size_t)b * c * N;
  float s = 0.f;
  for (int ch = 0; ch < c; ch += 8) {
#pragma unroll
    for (int u = 0; u < 8; ++u) { float v = P[(size_t)(ch + u) * N + n]; s = fmaf(v, v, s); }
  }
  float* out = ws + (which ? RNY_OFF : RNX_OFF) + t.ro[L] + b * N;
  out[n] = 1.0f / (sqrtf(s) + EPSC);
}

// ---------------- K3: per-channel means ----------------
__global__ void k_mu(float* __restrict__ ws, Tabs t) {
  // grid (128, 16, 4), block 256 = 4 waves; wave per channel, lanes over n
  int L = blockIdx.z;
  int c = t.c[L], N = t.N[L];
  int z = blockIdx.y, which = z >> 3, b = z & 7;
  int wv = threadIdx.x >> 6, lane = threadIdx.x & 63;
  int ch = blockIdx.x * 4 + wv;
  if (ch >= c) return;
  const float* P = ws + (which ? t.yoff[L] : t.xoff[L]) + ((size_t)b * c + ch) * N;
  float s = 0.f;
  for (int n = lane; n < N; n += 64) s += P[n];
#pragma unroll
  for (int off = 32; off; off >>= 1) s += __shfl_down(s, off, 64);
  if (lane == 0) (ws + (which ? MUY_OFF : MUX_OFF))[t.mo[L] + b * c + ch] = s * (1.0f / N);
}

// ---------------- K4: cosine distance + fused row/col mins ----------------
__global__ __launch_bounds__(256) void k_cosmin(float* __restrict__ ws, Tabs t) {
  // grid (16,16,32=L*8+b), block (16,16); 64x64 tile, 4x4 per thread
  __shared__ float As[32][68];
  __shared__ float Bs[32][68];
  __shared__ float cred[16][65];
  int z = blockIdx.z, L = z >> 3, b = z & 7;
  int c = t.c[L], N = t.N[L];
  const float* X = ws + t.xoff[L] + (size_t)b * c * N;
  const float* Y = ws + t.yoff[L] + (size_t)b * c * N;
  int i0 = blockIdx.x * 64, j0 = blockIdx.y * 64;
  int tx = threadIdx.x, ty = threadIdx.y;
  int tid = ty * 16 + tx;
  int il = tid & 63, kb = tid >> 6;
  float acc[4][4] = {};
  for (int k0 = 0; k0 < c; k0 += 32) {
#pragma unroll
    for (int r = 0; r < 8; ++r) {
      int kk = kb + r * 4;
      int gi = i0 + il, gj = j0 + il;
      const float* xr = X + (size_t)(k0 + kk) * N;
      const float* yr = Y + (size_t)(k0 + kk) * N;
      As[kk][il] = (gi < N) ? xr[gi] : 0.f;
      Bs[kk][il] = (gj < N) ? yr[gj] : 0.f;
    }
    __syncthreads();
#pragma unroll
    for (int kk = 0; kk < 32; ++kk) {
      float4 a4 = *(const float4*)&As[kk][ty * 4];
      float4 b4 = *(const float4*)&Bs[kk][tx * 4];
      float a[4] = {a4.x, a4.y, a4.z, a4.w};
      float bb[4] = {b4.x, b4.y, b4.z, b4.w};
#pragma unroll
      for (int ii = 0; ii < 4; ++ii)
#pragma unroll
        for (int jj = 0; jj < 4; ++jj) acc[ii][jj] = fmaf(a[ii], bb[jj], acc[ii][jj]);
    }
    __syncthreads();
  }
  const float* rnxp = ws + RNX_OFF + t.ro[L] + b * N;
  const float* rnyp = ws + RNY_OFF + t.ro[L] + b * N;
  float rnx[4], rny[4];
#pragma unroll
  for (int ii = 0; ii < 4; ++ii) {
    int i = i0 + ty * 4 + ii;
    rnx[ii] = (i < N) ? rnxp[i] : 0.f;
    int j = j0 + tx * 4 + ii;
    rny[ii] = (j < N) ? rnyp[j] : 0.f;
  }
  const float INFV = __uint_as_float(0x7f800000u);
  float rmin_l[4] = {INFV, INFV, INFV, INFV};
  float cmin_l[4] = {INFV, INFV, INFV, INFV};
#pragma unroll
  for (int ii = 0; ii < 4; ++ii) {
    int i = i0 + ty * 4 + ii;
    bool iv = i < N;
#pragma unroll
    for (int jj = 0; jj < 4; ++jj) {
      int j = j0 + tx * 4 + jj;
      float d = 1.0f - acc[ii][jj] * rnx[ii] * rny[jj];
      if (!(iv && (j < N))) d = INFV;
      rmin_l[ii] = fminf(rmin_l[ii], d);
      cmin_l[jj] = fminf(cmin_l[jj], d);
    }
  }
  // row mins: reduce across tx (16 contiguous lanes) via shuffle, then atomic
#pragma unroll
  for (int off = 8; off; off >>= 1)
#pragma unroll
    for (int ii = 0; ii < 4; ++ii) rmin_l[ii] = fminf(rmin_l[ii], __shfl_down(rmin_l[ii], off, 16));
  unsigned* rminp = (unsigned*)(ws + RMIN_OFF) + t.ro[L] + b * N;
  if (tx == 0) {
#pragma unroll
    for (int ii = 0; ii < 4; ++ii) {
      int i = i0 + ty * 4 + ii;
      if (i < N) atomicMin(&rminp[i], __float_as_uint(rmin_l[ii]));
    }
  }
  // col mins: reduce across ty via LDS
#pragma unroll
  for (int jj = 0; jj < 4; ++jj) cred[ty][tx * 4 + jj] = cmin_l[jj];
  __syncthreads();
  unsigned* cminp = (unsigned*)(ws + CMIN_OFF) + t.ro[L] + b * N;
  if (tid < 64) {
    float m = INFV;
#pragma unroll
    for (int tt = 0; tt < 16; ++tt) m = fminf(m, cred[tt][tid]);
    int gj = j0 + tid;
    if (gj < N) atomicMin(&cminp[gj], __float_as_uint(m));
  }
}

// ---------------- K5: fused Gx/Gy + |covX - covY| sum ----------------
__global__ __launch_bounds__(256) void k_cov(float* __restrict__ ws, Tabs t) {
  // grid (8,8,32), block (16,16); 64x64 channel tile, 4x4 per thread, X and Y fused
  __shared__ float XA[32][68], XB[32][68], YA[32][68], YB[32][68];
  __shared__ float wsum[4];
  int z = blockIdx.z, L = z >> 3, b = z & 7;
  int c = t.c[L], N = t.N[L];
  int ca = c >> 6;
  if ((int)blockIdx.x >= ca || (int)blockIdx.y >= ca) return;
  int a0 = blockIdx.x * 64, b0 = blockIdx.y * 64;
  const float* X = ws + t.xoff[L] + (size_t)b * c * N;
  const float* Y = ws + t.yoff[L] + (size_t)b * c * N;
  int tx = threadIdx.x, ty = threadIdx.y, tid = ty * 16 + tx;
  int nn_l = tid & 31, ch_l = tid >> 5;
  float gx[4][4] = {}, gy[4][4] = {};
  for (int n0 = 0; n0 < N; n0 += 32) {
    int n = n0 + nn_l;
    bool nv = n < N;
#pragma unroll
    for (int r = 0; r < 8; ++r) {
      int ch = ch_l + r * 8;
      XA[nn_l][ch] = nv ? X[(size_t)(a0 + ch) * N + n] : 0.f;
      XB[nn_l][ch] = nv ? X[(size_t)(b0 + ch) * N + n] : 0.f;
      YA[nn_l][ch] = nv ? Y[(size_t)(a0 + ch) * N + n] : 0.f;
      YB[nn_l][ch] = nv ? Y[(size_t)(b0 + ch) * N + n] : 0.f;
    }
    __syncthreads();
#pragma unroll
    for (int nn = 0; nn < 32; ++nn) {
      float4 xa = *(const float4*)&XA[nn][ty * 4];
      float4 xb = *(const float4*)&XB[nn][tx * 4];
      float4 ya = *(const float4*)&YA[nn][ty * 4];
      float4 yb = *(const float4*)&YB[nn][tx * 4];
      float xav[4] = {xa.x, xa.y, xa.z, xa.w}, xbv[4] = {xb.x, xb.y, xb.z, xb.w};
      float yav[4] = {ya.x, ya.y, ya.z, ya.w}, ybv[4] = {yb.x, yb.y, yb.z, yb.w};
#pragma unroll
      for (int ii = 0; ii < 4; ++ii)
#pragma unroll
        for (int jj = 0; jj < 4; ++jj) {
          gx[ii][jj] = fmaf(xav[ii], xbv[jj], gx[ii][jj]);
          gy[ii][jj] = fmaf(yav[ii], ybv[jj], gy[ii][jj]);
        }
    }
    __syncthreads();
  }
  const float* mux = ws + MUX_OFF + t.mo[L] + (size_t)b * c;
  const float* muy = ws + MUY_OFF + t.mo[L] + (size_t)b * c;
  float mxa[4], mxb[4], mya[4], myb[4];
#pragma unroll
  for (int ii = 0; ii < 4; ++ii) {
    mxa[ii] = mux[a0 + ty * 4 + ii];
    mxb[ii] = mux[b0 + tx * 4 + ii];
    mya[ii] = muy[a0 + ty * 4 + ii];
    myb[ii] = muy[b0 + tx * 4 + ii];
  }
  float fN = (float)N, inv1 = 1.0f / (float)(N - 1);
  float s = 0.f;
#pragma unroll
  for (int ii = 0; ii < 4; ++ii)
#pragma unroll
    for (int jj = 0; jj < 4; ++jj) {
      float cx = (gx[ii][jj] - fN * mxa[ii] * mxb[jj]) * inv1;
      float cy = (gy[ii][jj] - fN * mya[ii] * myb[jj]) * inv1;
      s += fabsf(cx - cy);
    }
#pragma unroll
  for (int off = 32; off; off >>= 1) s += __shfl_down(s, off, 64);
  if ((tid & 63) == 0) wsum[tid >> 6] = s;
  __syncthreads();
  if (tid == 0) atomicAdd(&ws[COVS_OFF + z], wsum[0] + wsum[1] + wsum[2] + wsum[3]);
}

// ---------------- K6: per-(L,b) loss terms ----------------
__global__ void k_final(float* __restrict__ ws, Tabs t) {
  __shared__ float red[4];
  int z = blockIdx.x, L = z >> 3, b = z & 7;
  int c = t.c[L], N = t.N[L];
  const unsigned* rmin = (const unsigned*)(ws + RMIN_OFF) + t.ro[L] + b * N;
  const unsigned* cmin = (const unsigned*)(ws + CMIN_OFF) + t.ro[L] + b * N;
  const float* mux = ws + MUX_OFF + t.mo[L] + (size_t)b * c;
  const float* muy = ws + MUY_OFF + t.mo[L] + (size_t)b * c;
  int tid = threadIdx.x;
  float sr = 0.f, sc = 0.f, sm = 0.f;
  for (int n = tid; n < N; n += 256) {
    sr += __uint_as_float(rmin[n]);
    sc += __uint_as_float(cmin[n]);
  }
  for (int ch = tid; ch < c; ch += 256) sm += fabsf(mux[ch] - muy[ch]);
  float vals[3] = {sr, sc, sm};
  float tot[3] = {0.f, 0.f, 0.f};
  for (int q = 0; q < 3; ++q) {
    float v = vals[q];
#pragma unroll
    for (int off = 32; off; off >>= 1) v += __shfl_down(v, off, 64);
    if ((tid & 63) == 0) red[tid >> 6] = v;
    __syncthreads();
    if (tid == 0) tot[q] = red[0] + red[1] + red[2] + red[3];
    __syncthreads();
  }
  if (tid == 0) {
    float style = fmaxf(tot[0] / (float)N, tot[1] / (float)N);
    float mu_d = tot[2] / (float)c;
    float cov = ws[COVS_OFF + z] / ((float)c * (float)c);
    atomicAdd(&ws[ACC_OFF], style + mu_d + cov);
  }
}

__global__ void k_out(const float* __restrict__ ws, float* __restrict__ out) {
  if (threadIdx.x == 0 && blockIdx.x == 0) out[0] = ws[ACC_OFF] * 0.125f;
}

extern "C" void kernel_launch(void* const* d_in, const int* in_sizes, int n_in,
                              void* d_out, int out_size, void* d_ws, size_t ws_size,
                              hipStream_t stream) {
  (void)in_sizes; (void)n_in; (void)out_size; (void)ws_size;
  static const int LC[4] = {64, 128, 256, 512};
  static const int LN[4] = {1000, 1000, 1000, 1024};
  static const int LHW[4] = {65536, 16384, 4096, 1024};
  static const unsigned XO[4] = {0u, 512000u, 1536000u, 3584000u};
  static const unsigned YO[4] = {7778304u, 8290304u, 9314304u, 11362304u};
  static const int RO[4] = {0, 8000, 16000, 24000};
  static const int MO[4] = {0, 512, 1536, 3584};

  float* ws = (float*)d_ws;
  Tabs t;
  for (int L = 0; L < 4; ++L) {
    t.c[L] = LC[L]; t.N[L] = LN[L];
    t.xoff[L] = XO[L]; t.yoff[L] = YO[L];
    t.ro[L] = RO[L]; t.mo[L] = MO[L];
  }

  k_init<<<dim3(252), dim3(256), 0, stream>>>(ws);
  for (int L = 0; L < 4; ++L) {
    const float* tf = (const float*)d_in[2 * L];
    const float* gf = (const float*)d_in[2 * L + 1];
    const int* idx = (L < 3) ? (const int*)d_in[8 + L] : nullptr;
    dim3 g((LN[L] + 255) / 256, LC[L], 16);
    k_gather<<<g, dim3(256), 0, stream>>>(tf, gf, idx, ws + XO[L], ws + YO[L], LC[L], LHW[L], LN[L]);
  }
  k_rnorm<<<dim3(4, 16, 4), dim3(256), 0, stream>>>(ws, t);
  k_mu<<<dim3(128, 16, 4), dim3(256), 0, stream>>>(ws, t);
  k_cosmin<<<dim3(16, 16, 32), dim3(16, 16), 0, stream>>>(ws, t);
  k_cov<<<dim3(8, 8, 32), dim3(16, 16), 0, stream>>>(ws, t);
  k_final<<<dim3(32), dim3(256), 0, stream>>>(ws, t);
  k_out<<<dim3(1), dim3(64), 0, stream>>>(ws, (float*)d_out);
}

// Round 2
// 624.699 us; speedup vs baseline: 1.8959x; 1.8959x over previous
//
#include <hip/hip_runtime.h>
#include <cstdint>
#include <cstddef>

#define EPSC 1e-10f
typedef unsigned short u16;
typedef unsigned int u32;
typedef __attribute__((ext_vector_type(8))) short bf16x8;
typedef __attribute__((ext_vector_type(4))) float f32x4;

// ---- workspace layout ----
// bf16 element offsets (2B units)
#define XTX_B 0u          // (c,1024) layout, X, per level/b
#define XTY_B 7864320u    // (c,1024) layout, Y
#define XNX_B 15728640u   // (1024,c) layout, X
#define XNY_B 23592960u   // (1024,c) layout, Y
// float offsets (4B units); starts at byte 62914560
#define FB 15728640u
#define RNX_OFF (FB + 0u)        // 32 * 1024
#define RNY_OFF (FB + 32768u)
#define RMIN_OFF (FB + 65536u)   // 32 * 1024
#define CMIN_OFF (FB + 98304u)
#define MUX_OFF (FB + 131072u)   // 7680
#define MUY_OFF (FB + 138752u)
#define COVS_OFF (FB + 146432u)  // 32
#define ACC_OFF (FB + 146464u)
// total ~63.5 MB (round 1 used 62.8 MB OK)

struct Tabs { int c[4], N[4], mo[4]; u32 off[4]; };

__device__ __forceinline__ u16 f2bf(float f) {
  u32 u = __float_as_uint(f);
  u = (u + 0x7fffu + ((u >> 16) & 1u)) >> 16;
  return (u16)u;
}
__device__ __forceinline__ float bf2f(u16 h) { return __uint_as_float(((u32)h) << 16); }

// ---------------- K0: init mins/accumulators ----------------
__global__ void k_init(float* __restrict__ wsf) {
  int i = blockIdx.x * blockDim.x + threadIdx.x;
  if (i < 65536) ((unsigned*)(wsf + RMIN_OFF))[i] = 0x7f800000u; // RMIN+CMIN -> +inf
  if (i < 33) wsf[COVS_OFF + i] = 0.f;                           // COVS[32] + ACC
}

// ---------------- K1: gather -> bf16, two layouts, via LDS transpose ----------------
__global__ void k_gather(const float* __restrict__ tsrc, const float* __restrict__ gsrc,
                         const int* __restrict__ idx,
                         u16* __restrict__ xt, u16* __restrict__ yt,
                         u16* __restrict__ xn, u16* __restrict__ yn,
                         int c, int hw, int N) {
  // grid (16 n-tiles, c/64 ch-tiles, 16=which*8+b), block 256; 64ch x 64n tile
  __shared__ float Ls[64 * 67];
  int z = blockIdx.z, which = z >> 3, b = z & 7;
  int c0 = blockIdx.y * 64, n0 = blockIdx.x * 64;
  int tid = threadIdx.x;
  const float* src = which ? gsrc : tsrc;
  u16* dt = (which ? yt : xt) + (size_t)b * c * 1024;
  u16* dn = (which ? yn : xn) + (size_t)b * c * 1024;
  int nl = tid & 63, cb = tid >> 6;
  int n = n0 + nl;
  bool nv = n < N;
  int sp = nv ? (idx ? idx[b * N + n] : n) : 0;
  const float* sbase = src + ((size_t)b * c + c0) * hw;
#pragma unroll
  for (int r = 0; r < 16; ++r) {
    int ch = cb + r * 4;
    Ls[ch * 67 + nl] = nv ? sbase[(size_t)ch * hw + sp] : 0.f;
  }
  __syncthreads();
  // write (c,1024) layout: lanes along n, coalesced
#pragma unroll
  for (int r = 0; r < 16; ++r) {
    int ch = cb + r * 4;
    dt[(size_t)(c0 + ch) * 1024 + n] = f2bf(Ls[ch * 67 + nl]);
  }
  // write (1024,c) layout: lanes along ch, coalesced; LDS col read stride 67 -> conflict-free
#pragma unroll
  for (int r = 0; r < 16; ++r) {
    int nw = cb + r * 4;
    int chw = nl;
    dn[(size_t)(n0 + nw) * c + c0 + chw] = f2bf(Ls[chw * 67 + nw]);
  }
}

// ---------------- K2: reciprocal norms from (c,1024) bf16 ----------------
__global__ void k_rnorm(const u16* __restrict__ bfb, float* __restrict__ wsf, Tabs t) {
  int L = blockIdx.z;
  int c = t.c[L];
  int zy = blockIdx.y, which = zy >> 3, b = zy & 7;
  int n = blockIdx.x * 256 + threadIdx.x; // 0..1023
  const u16* P = bfb + (which ? XTY_B : XTX_B) + t.off[L] + (size_t)b * c * 1024;
  float s = 0.f;
  for (int ch = 0; ch < c; ch += 4) {
#pragma unroll
    for (int u = 0; u < 4; ++u) {
      float v = bf2f(P[(size_t)(ch + u) * 1024 + n]);
      s = fmaf(v, v, s);
    }
  }
  int z = L * 8 + b;
  wsf[(which ? RNY_OFF : RNX_OFF) + (size_t)z * 1024 + n] = 1.0f / (sqrtf(s) + EPSC);
}

// ---------------- K3: per-channel means from (c,1024) bf16 ----------------
__global__ void k_mu(const u16* __restrict__ bfb, float* __restrict__ wsf, Tabs t) {
  int L = blockIdx.z;
  int c = t.c[L], N = t.N[L];
  int zy = blockIdx.y, which = zy >> 3, b = zy & 7;
  int wv = threadIdx.x >> 6, lane = threadIdx.x & 63;
  int ch = blockIdx.x * 4 + wv;
  if (ch >= c) return;
  const u16* P = bfb + (which ? XTY_B : XTX_B) + t.off[L] + ((size_t)b * c + ch) * 1024;
  float s = 0.f;
  for (int n = lane; n < 1024; n += 64) s += bf2f(P[n]); // padded tail is zero
#pragma unroll
  for (int off = 32; off; off >>= 1) s += __shfl_down(s, off, 64);
  if (lane == 0) wsf[(which ? MUY_OFF : MUX_OFF) + t.mo[L] + (size_t)b * c + ch] = s * (1.0f / N);
}

// ---------------- K4: MFMA cosine-dist + fused row/col mins ----------------
__global__ __launch_bounds__(256) void k_cosmin(const u16* __restrict__ bfb, float* __restrict__ wsf, Tabs t) {
  // grid (8,8,32=L*8+b), block 256 = 4 waves (2x2); 128x128 D-tile; KT=64
  __shared__ __align__(16) u16 As[128 * 72];
  __shared__ __align__(16) u16 Bs[128 * 72];
  int z = blockIdx.z, L = z >> 3, b = z & 7;
  int c = t.c[L], N = t.N[L];
  const u16* X = bfb + XNX_B + t.off[L] + (size_t)b * c * 1024;
  const u16* Y = bfb + XNY_B + t.off[L] + (size_t)b * c * 1024;
  int i0 = blockIdx.x * 128, j0 = blockIdx.y * 128;
  int tid = threadIdx.x, lane = tid & 63, w = tid >> 6;
  int wi = w >> 1, wj = w & 1, q = lane >> 4, cl = lane & 15;
  f32x4 acc[4][4] = {};
  int srow = tid >> 3, sch = tid & 7;
  for (int k0 = 0; k0 < c; k0 += 64) {
#pragma unroll
    for (int rep = 0; rep < 4; ++rep) {
      int row = srow + rep * 32;
      uint4 va = *(const uint4*)(X + (size_t)(i0 + row) * c + k0 + sch * 8);
      uint4 vb = *(const uint4*)(Y + (size_t)(j0 + row) * c + k0 + sch * 8);
      *(uint4*)(As + row * 72 + sch * 8) = va;
      *(uint4*)(Bs + row * 72 + sch * 8) = vb;
    }
    __syncthreads();
#pragma unroll
    for (int h = 0; h < 2; ++h) {
      bf16x8 af[4], bq[4];
#pragma unroll
      for (int ti = 0; ti < 4; ++ti)
        af[ti] = *(const bf16x8*)(As + (wi * 64 + ti * 16 + cl) * 72 + h * 32 + q * 8);
#pragma unroll
      for (int tj = 0; tj < 4; ++tj)
        bq[tj] = *(const bf16x8*)(Bs + (wj * 64 + tj * 16 + cl) * 72 + h * 32 + q * 8);
#pragma unroll
      for (int ti = 0; ti < 4; ++ti)
#pragma unroll
        for (int tj = 0; tj < 4; ++tj)
          acc[ti][tj] = __builtin_amdgcn_mfma_f32_16x16x32_bf16(af[ti], bq[tj], acc[ti][tj], 0, 0, 0);
    }
    __syncthreads();
  }
  // epilogue: d = 1 - dot*rnx*rny ; C/D layout: col=lane&15, row=q*4+reg
  const float* rnx = wsf + RNX_OFF + (size_t)z * 1024;
  const float* rny = wsf + RNY_OFF + (size_t)z * 1024;
  unsigned* rminp = (unsigned*)(wsf + RMIN_OFF) + (size_t)z * 1024;
  unsigned* cminp = (unsigned*)(wsf + CMIN_OFF) + (size_t)z * 1024;
  const float INFV = __uint_as_float(0x7f800000u);
  int colg[4]; float rnyv[4]; float colmin[4];
#pragma unroll
  for (int tj = 0; tj < 4; ++tj) {
    colg[tj] = j0 + wj * 64 + tj * 16 + cl;
    rnyv[tj] = rny[colg[tj]];
    colmin[tj] = INFV;
  }
#pragma unroll
  for (int ti = 0; ti < 4; ++ti) {
#pragma unroll
    for (int r = 0; r < 4; ++r) {
      int rowg = i0 + wi * 64 + ti * 16 + q * 4 + r;
      float rx = rnx[rowg];
      bool rv = rowg < N;
      float rmin = INFV;
#pragma unroll
      for (int tj = 0; tj < 4; ++tj) {
        float d = 1.0f - acc[ti][tj][r] * rx * rnyv[tj];
        if (!rv || colg[tj] >= N) d = INFV;
        rmin = fminf(rmin, d);
        colmin[tj] = fminf(colmin[tj], d);
      }
      rmin = fminf(rmin, __shfl_xor(rmin, 1, 64));
      rmin = fminf(rmin, __shfl_xor(rmin, 2, 64));
      rmin = fminf(rmin, __shfl_xor(rmin, 4, 64));
      rmin = fminf(rmin, __shfl_xor(rmin, 8, 64));
      if (cl == 0 && rv) atomicMin(&rminp[rowg], __float_as_uint(rmin));
    }
  }
#pragma unroll
  for (int tj = 0; tj < 4; ++tj) {
    float cm = colmin[tj];
    cm = fminf(cm, __shfl_xor(cm, 16, 64));
    cm = fminf(cm, __shfl_xor(cm, 32, 64));
    if (q == 0 && colg[tj] < N) atomicMin(&cminp[colg[tj]], __float_as_uint(cm));
  }
}

// ---------------- K5: MFMA Gx/Gy + fused |covX-covY| sum ----------------
__global__ __launch_bounds__(256) void k_cov(const u16* __restrict__ bfb, float* __restrict__ wsf, Tabs t) {
  // grid (4,4,32), block 256; 128x128 G-tile, X and Y fused; KT=32
  __shared__ __align__(16) u16 SXA[128 * 40], SXB[128 * 40], SYA[128 * 40], SYB[128 * 40];
  __shared__ float wsum[4];
  int z = blockIdx.z, L = z >> 3, b = z & 7;
  int c = t.c[L], N = t.N[L];
  int ca = (c + 127) >> 7;
  if ((int)blockIdx.x >= ca || (int)blockIdx.y >= ca) return;
  int a0 = blockIdx.x * 128, b0 = blockIdx.y * 128;
  const u16* XT = bfb + XTX_B + t.off[L] + (size_t)b * c * 1024;
  const u16* YT = bfb + XTY_B + t.off[L] + (size_t)b * c * 1024;
  int tid = threadIdx.x, lane = tid & 63, w = tid >> 6;
  int wi = w >> 1, wj = w & 1, q = lane >> 4, cl = lane & 15;
  f32x4 gx[4][4] = {}, gy[4][4] = {};
  int srow = tid >> 2, sch = tid & 3;
  for (int k0 = 0; k0 < 1024; k0 += 32) { // padded samples are zero -> exact G
#pragma unroll
    for (int rep = 0; rep < 2; ++rep) {
      int rr = srow + rep * 64;
      int ra = a0 + rr, rb = b0 + rr;
      uint4 zz = make_uint4(0u, 0u, 0u, 0u);
      uint4 xa = (ra < c) ? *(const uint4*)(XT + (size_t)ra * 1024 + k0 + sch * 8) : zz;
      uint4 xb = (rb < c) ? *(const uint4*)(XT + (size_t)rb * 1024 + k0 + sch * 8) : zz;
      uint4 ya = (ra < c) ? *(const uint4*)(YT + (size_t)ra * 1024 + k0 + sch * 8) : zz;
      uint4 yb = (rb < c) ? *(const uint4*)(YT + (size_t)rb * 1024 + k0 + sch * 8) : zz;
      *(uint4*)(SXA + rr * 40 + sch * 8) = xa;
      *(uint4*)(SXB + rr * 40 + sch * 8) = xb;
      *(uint4*)(SYA + rr * 40 + sch * 8) = ya;
      *(uint4*)(SYB + rr * 40 + sch * 8) = yb;
    }
    __syncthreads();
    bf16x8 af[4], bq[4];
#pragma unroll
    for (int ti = 0; ti < 4; ++ti) af[ti] = *(const bf16x8*)(SXA + (wi * 64 + ti * 16 + cl) * 40 + q * 8);
#pragma unroll
    for (int tj = 0; tj < 4; ++tj) bq[tj] = *(const bf16x8*)(SXB + (wj * 64 + tj * 16 + cl) * 40 + q * 8);
#pragma unroll
    for (int ti = 0; ti < 4; ++ti)
#pragma unroll
      for (int tj = 0; tj < 4; ++tj)
        gx[ti][tj] = __builtin_amdgcn_mfma_f32_16x16x32_bf16(af[ti], bq[tj], gx[ti][tj], 0, 0, 0);
#pragma unroll
    for (int ti = 0; ti < 4; ++ti) af[ti] = *(const bf16x8*)(SYA + (wi * 64 + ti * 16 + cl) * 40 + q * 8);
#pragma unroll
    for (int tj = 0; tj < 4; ++tj) bq[tj] = *(const bf16x8*)(SYB + (wj * 64 + tj * 16 + cl) * 40 + q * 8);
#pragma unroll
    for (int ti = 0; ti < 4; ++ti)
#pragma unroll
      for (int tj = 0; tj < 4; ++tj)
        gy[ti][tj] = __builtin_amdgcn_mfma_f32_16x16x32_bf16(af[ti], bq[tj], gy[ti][tj], 0, 0, 0);
    __syncthreads();
  }
  const float* mux = wsf + MUX_OFF + t.mo[L] + (size_t)b * c;
  const float* muy = wsf + MUY_OFF + t.mo[L] + (size_t)b * c;
  float fN = (float)N, inv1 = 1.0f / (float)(N - 1);
  float mxb[4], myb[4]; int bcol[4];
#pragma unroll
  for (int tj = 0; tj < 4; ++tj) {
    bcol[tj] = b0 + wj * 64 + tj * 16 + cl;
    bool bv = bcol[tj] < c;
    mxb[tj] = bv ? mux[bcol[tj]] : 0.f;
    myb[tj] = bv ? muy[bcol[tj]] : 0.f;
  }
  float s = 0.f;
#pragma unroll
  for (int ti = 0; ti < 4; ++ti) {
#pragma unroll
    for (int r = 0; r < 4; ++r) {
      int arow = a0 + wi * 64 + ti * 16 + q * 4 + r;
      bool av = arow < c;
      float mxa = av ? mux[arow] : 0.f;
      float mya = av ? muy[arow] : 0.f;
#pragma unroll
      for (int tj = 0; tj < 4; ++tj) {
        if (av && bcol[tj] < c) {
          float cx = (gx[ti][tj][r] - fN * mxa * mxb[tj]) * inv1;
          float cy = (gy[ti][tj][r] - fN * mya * myb[tj]) * inv1;
          s += fabsf(cx - cy);
        }
      }
    }
  }
  s += __shfl_xor(s, 1, 64);
  s += __shfl_xor(s, 2, 64);
  s += __shfl_xor(s, 4, 64);
  s += __shfl_xor(s, 8, 64);
  s += __shfl_xor(s, 16, 64);
  s += __shfl_xor(s, 32, 64);
  if (lane == 0) wsum[w] = s;
  __syncthreads();
  if (tid == 0) atomicAdd(&wsf[COVS_OFF + z], wsum[0] + wsum[1] + wsum[2] + wsum[3]);
}

// ---------------- K6: per-(L,b) loss terms ----------------
__global__ void k_final(float* __restrict__ wsf, Tabs t) {
  __shared__ float red[4];
  int z = blockIdx.x, L = z >> 3, b = z & 7;
  int c = t.c[L], N = t.N[L];
  const unsigned* rmin = (const unsigned*)(wsf + RMIN_OFF) + (size_t)z * 1024;
  const unsigned* cmin = (const unsigned*)(wsf + CMIN_OFF) + (size_t)z * 1024;
  const float* mux = wsf + MUX_OFF + t.mo[L] + (size_t)b * c;
  const float* muy = wsf + MUY_OFF + t.mo[L] + (size_t)b * c;
  int tid = threadIdx.x;
  float sr = 0.f, sc = 0.f, sm = 0.f;
  for (int n = tid; n < N; n += 256) {
    sr += __uint_as_float(rmin[n]);
    sc += __uint_as_float(cmin[n]);
  }
  for (int ch = tid; ch < c; ch += 256) sm += fabsf(mux[ch] - muy[ch]);
  float vals[3] = {sr, sc, sm};
  float tot[3] = {0.f, 0.f, 0.f};
  for (int qq = 0; qq < 3; ++qq) {
    float v = vals[qq];
#pragma unroll
    for (int off = 32; off; off >>= 1) v += __shfl_down(v, off, 64);
    if ((tid & 63) == 0) red[tid >> 6] = v;
    __syncthreads();
    if (tid == 0) tot[qq] = red[0] + red[1] + red[2] + red[3];
    __syncthreads();
  }
  if (tid == 0) {
    float style = fmaxf(tot[0] / (float)N, tot[1] / (float)N);
    float mu_d = tot[2] / (float)c;
    float cov = wsf[COVS_OFF + z] / ((float)c * (float)c);
    atomicAdd(&wsf[ACC_OFF], style + mu_d + cov);
  }
}

__global__ void k_out(const float* __restrict__ wsf, float* __restrict__ out) {
  if (threadIdx.x == 0 && blockIdx.x == 0) out[0] = wsf[ACC_OFF] * 0.125f;
}

extern "C" void kernel_launch(void* const* d_in, const int* in_sizes, int n_in,
                              void* d_out, int out_size, void* d_ws, size_t ws_size,
                              hipStream_t stream) {
  (void)in_sizes; (void)n_in; (void)out_size; (void)ws_size;
  static const int LC[4] = {64, 128, 256, 512};
  static const int LN[4] = {1000, 1000, 1000, 1024};
  static const int LHW[4] = {65536, 16384, 4096, 1024};
  static const u32 LOFF[4] = {0u, 524288u, 1572864u, 3670016u}; // c*1024*8 cumulative
  static const int MO[4] = {0, 512, 1536, 3584};

  float* wsf = (float*)d_ws;
  u16* bfb = (u16*)d_ws;
  Tabs t;
  for (int L = 0; L < 4; ++L) {
    t.c[L] = LC[L]; t.N[L] = LN[L]; t.mo[L] = MO[L]; t.off[L] = LOFF[L];
  }

  k_init<<<dim3(256), dim3(256), 0, stream>>>(wsf);
  for (int L = 0; L < 4; ++L) {
    const float* tf = (const float*)d_in[2 * L];
    const float* gf = (const float*)d_in[2 * L + 1];
    const int* idx = (L < 3) ? (const int*)d_in[8 + L] : nullptr;
    dim3 g(16, LC[L] / 64, 16);
    k_gather<<<g, dim3(256), 0, stream>>>(tf, gf, idx,
                                          bfb + XTX_B + LOFF[L], bfb + XTY_B + LOFF[L],
                                          bfb + XNX_B + LOFF[L], bfb + XNY_B + LOFF[L],
                                          LC[L], LHW[L], LN[L]);
  }
  k_rnorm<<<dim3(4, 16, 4), dim3(256), 0, stream>>>(bfb, wsf, t);
  k_mu<<<dim3(128, 16, 4), dim3(256), 0, stream>>>(bfb, wsf, t);
  k_cosmin<<<dim3(8, 8, 32), dim3(256), 0, stream>>>(bfb, wsf, t);
  k_cov<<<dim3(4, 4, 32), dim3(256), 0, stream>>>(bfb, wsf, t);
  k_final<<<dim3(32), dim3(256), 0, stream>>>(wsf, t);
  k_out<<<dim3(1), dim3(64), 0, stream>>>(wsf, (float*)d_out);
}